// Round 14
// baseline (243.476 us; speedup 1.0000x reference)
//
#include <hip/hip_runtime.h>
#include <math.h>

#define Bq 16
#define Sq 1024
#define Dq 128
#define Hq 8
#define DHq 16
#define DFFq 512
#define Lq 3
#define NCLS 6
#define NROWS (Bq * Sq)       // 16384
#define NX ((size_t)NROWS * Dq)   // 2,097,152 floats

// Q pre-scale: (1/sqrt(DH)) * log2(e), so softmax probs = 2^score (raw v_exp)
#define QSCL 0.36067376022224085f

typedef __attribute__((ext_vector_type(8))) short    bf16x8;
typedef __attribute__((ext_vector_type(4))) float    f32x4;
typedef __attribute__((ext_vector_type(4))) _Float16 f16x4;
typedef __attribute__((ext_vector_type(8))) _Float16 f16x8;
typedef __attribute__((ext_vector_type(2))) _Float16 f16x2;
typedef __attribute__((ext_vector_type(4))) ushort   u16x4;

__device__ inline ushort f32_to_bf16(float f) {
    union { float f; unsigned u; } v; v.f = f;
    unsigned r = v.u + 0x7fffu + ((v.u >> 16) & 1u);
    return (ushort)(r >> 16);
}

__device__ __forceinline__ float bf16_to_f32(ushort h) {
    union { unsigned u; float f; } v; v.u = ((unsigned)h) << 16;
    return v.f;
}

// raw 2^x via v_exp_f32 (ISA-guaranteed); avoids __expf's extra v_mul
__device__ __forceinline__ float exp2_raw(float x) {
    float r;
    asm("v_exp_f32 %0, %1" : "=v"(r) : "v"(x));
    return r;
}

__device__ __forceinline__ float rcp_fast(float x) {
    float r;
    asm("v_rcp_f32 %0, %1" : "=v"(r) : "v"(x));
    return r;
}

// pack two f32 -> f16x2 via v_cvt_pkrtz_f16_f32; builtin returns __fp16
// ext-vector, bit_cast to our _Float16 vector (same 4-byte layout).
__device__ __forceinline__ f16x2 pkrtz(float a, float b) {
    return __builtin_bit_cast(f16x2, __builtin_amdgcn_cvt_pkrtz(a, b));
}

// ---------------------------------------------------------------------------
// prep: LDS-tiled weight transposes (coalesced reads AND writes) + x cast.
// Wq PRE-SCALED by QSCL (ReLU commutes with positive scale).
// Grid 2081: blk 0..8 QKV, 9..20 W1 col-slices, 21..32 W2 row-slices,
// 33..2080 x-cast (vec4).
// ---------------------------------------------------------------------------
__global__ __launch_bounds__(256) void prep_kernel(
    const float* __restrict__ Wqp, const float* __restrict__ Wkp,
    const float* __restrict__ Wvp, const float* __restrict__ W1p,
    const float* __restrict__ W2p, const float* __restrict__ xp,
    ushort* __restrict__ wbf, ushort* __restrict__ xbf)
{
    __shared__ ushort tile[128 * 132];   // 33 KB; stride 132 (4-way, benign)
    const int blk = blockIdx.x;
    const int tid = threadIdx.x;

    if (blk < 33) {
        const float* S;
        int sld, dld;
        ushort* D;
        float scl = 1.0f;

        if (blk < 9) {                       // QKV: [128][128] -> [128][128]
            const int w = blk / 3, l = blk - w * 3;
            const float* src = (w == 0) ? Wqp : (w == 1) ? Wkp : Wvp;
            scl = (w == 0) ? QSCL : 1.0f;
            S   = src + (size_t)l * 16384;
            sld = 128;
            D   = wbf + (size_t)(w * 3 + l) * 16384;
            dld = 128;
        } else if (blk < 21) {               // W1: [128][512] col-slice t
            const int idx = blk - 9, l = idx >> 2, t = idx & 3;
            S   = W1p + (size_t)l * 65536 + t * 128;
            sld = 512;
            D   = wbf + 147456 + (size_t)l * 65536 + (size_t)t * 128 * 128;
            dld = 128;
        } else {                             // W2: [512][128] row-slice t
            const int idx = blk - 21, l = idx >> 2, t = idx & 3;
            S   = W2p + (size_t)l * 65536 + (size_t)t * 128 * 128;
            sld = 128;
            D   = wbf + 344064 + (size_t)l * 65536 + t * 128;
            dld = 512;
        }

        // phase 1: coalesced float4 reads of S rows -> tile[n][k] (bf16)
        #pragma unroll 4
        for (int i = 0; i < 16; ++i) {
            const int e4 = tid + i * 256;
            const int k  = e4 >> 5;
            const int n4 = (e4 & 31) * 4;
            const float4 v = *(const float4*)(S + (size_t)k * sld + n4);
            tile[(n4 + 0) * 132 + k] = f32_to_bf16(v.x * scl);
            tile[(n4 + 1) * 132 + k] = f32_to_bf16(v.y * scl);
            tile[(n4 + 2) * 132 + k] = f32_to_bf16(v.z * scl);
            tile[(n4 + 3) * 132 + k] = f32_to_bf16(v.w * scl);
        }
        __syncthreads();

        // phase 2: coalesced 8B stores of D rows (transposed data)
        const int k0 = (tid & 15) * 8;
        #pragma unroll
        for (int i = 0; i < 8; ++i) {
            const int n = (tid >> 4) + i * 16;
            const u16x4 a = *(const u16x4*)&tile[n * 132 + k0];
            const u16x4 b = *(const u16x4*)&tile[n * 132 + k0 + 4];
            *(u16x4*)(D + (size_t)n * dld + k0)     = a;
            *(u16x4*)(D + (size_t)n * dld + k0 + 4) = b;
        }
    } else {                                 // x cast, 4 elems/thread
        const size_t g = ((size_t)(blk - 33) * 256 + tid) * 4;
        const float4 xv = *(const float4*)(xp + g);
        u16x4 r;
        r[0] = f32_to_bf16(xv.x); r[1] = f32_to_bf16(xv.y);
        r[2] = f32_to_bf16(xv.z); r[3] = f32_to_bf16(xv.w);
        *(u16x4*)(xbf + g) = r;
    }
}

// ---------------------------------------------------------------------------
// Standalone QKV GEMM (layer 0 only). grid (256, 3).  [R3-proven]
// ---------------------------------------------------------------------------
__global__ __launch_bounds__(256) void gemm_qkv(
    const ushort* __restrict__ A,
    const ushort* __restrict__ wq, const ushort* __restrict__ wk,
    const ushort* __restrict__ wv,
    const float* __restrict__ bqp, const float* __restrict__ bkp,
    const float* __restrict__ bvp,
    _Float16* __restrict__ qo, _Float16* __restrict__ ko,
    _Float16* __restrict__ vo)
{
    __shared__ ushort As[64 * 40];
    __shared__ ushort Bs[128 * 40];

    const int sel  = blockIdx.y;
    const ushort* Bt   = (sel == 0) ? wq : (sel == 1) ? wk : wv;
    const float*  bias = (sel == 0) ? bqp : (sel == 1) ? bkp : bvp;
    const float   bscl = (sel == 0) ? QSCL : 1.0f;

    const int tid  = threadIdx.x;
    const int row0 = blockIdx.x * 64;
    const int wave = tid >> 6;
    const int lane = tid & 63;
    const int quad = lane >> 4;
    const int m16  = lane & 15;
    const int wm   = wave >> 1;
    const int wn   = wave & 1;

    const int sar = tid >> 2;
    const int sac = (tid & 3) * 8;

    f32x4 acc[2][4];
    #pragma unroll
    for (int i = 0; i < 2; ++i)
        #pragma unroll
        for (int j = 0; j < 4; ++j) acc[i][j] = (f32x4)0.f;

    const int r1 = tid >> 2, r2 = r1 + 64;

    // prologue: k0 = 0
    bf16x8 av  = *(const bf16x8*)(A  + (size_t)(row0 + sar) * 128 + sac);
    bf16x8 bv1 = *(const bf16x8*)(Bt + (size_t)r1 * 128 + sac);
    bf16x8 bv2 = *(const bf16x8*)(Bt + (size_t)r2 * 128 + sac);

    for (int k0 = 0; k0 < 128; k0 += 32) {
        __syncthreads();
        *(bf16x8*)&As[sar * 40 + sac] = av;
        *(bf16x8*)&Bs[r1 * 40 + sac]  = bv1;
        *(bf16x8*)&Bs[r2 * 40 + sac]  = bv2;
        __syncthreads();

        if (k0 < 96) {
            av  = *(const bf16x8*)(A  + (size_t)(row0 + sar) * 128 + k0 + 32 + sac);
            bv1 = *(const bf16x8*)(Bt + (size_t)r1 * 128 + k0 + 32 + sac);
            bv2 = *(const bf16x8*)(Bt + (size_t)r2 * 128 + k0 + 32 + sac);
        }

        bf16x8 af[2], bf[4];
        #pragma unroll
        for (int i = 0; i < 2; ++i)
            af[i] = *(const bf16x8*)&As[(32 * wm + 16 * i + m16) * 40 + quad * 8];
        #pragma unroll
        for (int j = 0; j < 4; ++j)
            bf[j] = *(const bf16x8*)&Bs[(64 * wn + 16 * j + m16) * 40 + quad * 8];
        #pragma unroll
        for (int i = 0; i < 2; ++i)
            #pragma unroll
            for (int j = 0; j < 4; ++j)
                acc[i][j] = __builtin_amdgcn_mfma_f32_16x16x32_bf16(af[i], bf[j], acc[i][j], 0, 0, 0);
    }

    #pragma unroll
    for (int i = 0; i < 2; ++i) {
        #pragma unroll
        for (int j = 0; j < 4; ++j) {
            const int col = 64 * wn + 16 * j + m16;
            const float bb = bias[col] * bscl;
            const int hh = col >> 4, dh = col & 15;
            #pragma unroll
            for (int r = 0; r < 4; ++r) {
                float val = fmaxf(acc[i][j][r] + bb, 0.f);
                const int gr = row0 + 32 * wm + 16 * i + quad * 4 + r;
                const int b = gr >> 10, s = gr & 1023;
                if (sel == 2) {
                    vo[(((size_t)b * Hq + hh) * DHq + dh) * Sq + s] = (_Float16)val;
                } else {
                    _Float16* outp = (sel == 0) ? qo : ko;
                    outp[(((size_t)b * Hq + hh) * Sq + s) * DHq + dh] = (_Float16)val;
                }
            }
        }
    }
}

// ---------------------------------------------------------------------------
// FUSED FFN BLOCK: LN1 -> (FFN1-chunk -> FFN2-partial)x4 -> LN2 + QKV.
// [R6-proven champion structure] This round: residual stream in bf16 —
// resid read is ushort (xbf0 for layer 0, xb for layers 1-2), xb write bf16.
// Saves ~20 MB of HBM traffic across the 3 layers.
// ---------------------------------------------------------------------------
__global__ __launch_bounds__(256, 3) void gemm_ffn_fused(
    const _Float16* __restrict__ o, const ushort* __restrict__ resid,
    const float* __restrict__ g1, const float* __restrict__ beta1,
    const ushort* __restrict__ W1t, const float* __restrict__ bias1,
    const ushort* __restrict__ W2t, const float* __restrict__ bias2,
    const float* __restrict__ g2, const float* __restrict__ beta2,
    ushort* __restrict__ xb,
    const ushort* __restrict__ wqn, const ushort* __restrict__ wkn,
    const ushort* __restrict__ wvn,
    const float* __restrict__ bqn, const float* __restrict__ bkn,
    const float* __restrict__ bvn,
    _Float16* __restrict__ qo, _Float16* __restrict__ ko,
    _Float16* __restrict__ vo, int do_next,
    const float* __restrict__ Wout, const float* __restrict__ bout,
    float* __restrict__ out, int last)
{
    __shared__ __align__(16) char smem[44544];
    ushort*    Af   = (ushort*)smem;                 // 32x136 bf16 (LN1 out)
    ushort*    Hcc  = (ushort*)(smem + 8704);        // 32x136 bf16 (h chunk)
    ushort*    Bs   = (ushort*)(smem + 17408);       // 128x72 staging
    float*     wo_s = (float*)(smem + 17408);        // overlays Bs (last, post-GEMM)
    _Float16*  vals = (_Float16*)(smem + 35840);     // 32x132 f16
    float*     mus  = (float*)(smem + 44288);
    float*     rsds = (float*)(smem + 44416);

    const int tid  = threadIdx.x;
    const int row0 = blockIdx.x * 32;
    const int wave = tid >> 6;
    const int lane = tid & 63;
    const int quad = lane >> 4;
    const int m16  = lane & 15;
    const int wm   = wave >> 1;          // row half: 16*wm
    const int wn   = wave & 1;           // col half: 64*wn
    const int sac  = (tid & 3) * 8;
    const int r1   = tid >> 2, r2 = r1 + 64;

    // ---- Phase A: LN1, 8 rows/wave; batch-issue all 16 global loads ----
    const int ca = lane * 2;
    const float2 gg  = *(const float2*)(g1 + ca);
    const float2 bt1 = *(const float2*)(beta1 + ca);
    f16x2   ovv[8];
    ushort2 rvv[8];
    #pragma unroll
    for (int it = 0; it < 8; ++it) {
        const size_t base = (size_t)(row0 + wave * 8 + it) * Dq;
        ovv[it] = *(const f16x2*)(o + base + ca);
        rvv[it] = *(const ushort2*)(resid + base + ca);
    }
    #pragma unroll
    for (int it = 0; it < 8; ++it) {
        const int rr = wave * 8 + it;
        const float v0 = (float)ovv[it][0] + bf16_to_f32(rvv[it].x);
        const float v1 = (float)ovv[it][1] + bf16_to_f32(rvv[it].y);

        float s = v0 + v1;
        #pragma unroll
        for (int off = 32; off > 0; off >>= 1) s += __shfl_xor(s, off, 64);
        const float mu = s * (1.f / 128.f);
        const float d0 = v0 - mu, d1 = v1 - mu;
        float vs = d0 * d0 + d1 * d1;
        #pragma unroll
        for (int off = 32; off > 0; off >>= 1) vs += __shfl_xor(vs, off, 64);
        const float rstd = rsqrtf(vs * (1.f / 128.f) + 1e-8f);

        const float rv0 = gg.x * d0 * rstd + bt1.x;
        const float rv1 = gg.y * d1 * rstd + bt1.y;
        ushort2 ab; ab.x = f32_to_bf16(rv0); ab.y = f32_to_bf16(rv1);
        *(ushort2*)&Af[rr * 136 + ca] = ab;
        f16x2 vv; vv[0] = (_Float16)rv0; vv[1] = (_Float16)rv1;
        *(f16x2*)&vals[rr * 132 + ca] = vv;
    }

    // ---- Unified 16-step pipeline: per chunk cc: FFN1 (2 steps) then
    //      FFN2 partial-K (2 steps). acc2 accumulates across all chunks. ----
    f32x4 acc[4], acc2[4];
    #pragma unroll
    for (int j = 0; j < 4; ++j) { acc[j] = (f32x4)0.f; acc2[j] = (f32x4)0.f; }

    // prologue: step 0 = W1 chunk 0, half 0
    bf16x8 w11 = *(const bf16x8*)(W1t + (size_t)r1 * 128 + sac);
    bf16x8 w12 = *(const bf16x8*)(W1t + (size_t)r1 * 128 + 32 + sac);
    bf16x8 w21 = *(const bf16x8*)(W1t + (size_t)r2 * 128 + sac);
    bf16x8 w22 = *(const bf16x8*)(W1t + (size_t)r2 * 128 + 32 + sac);

    #pragma unroll
    for (int t = 0; t < 16; ++t) {
        const int cc   = t >> 2;
        const int ph   = (t >> 1) & 1;     // 0 = FFN1 (W1), 1 = FFN2 (W2)
        const int half = t & 1;            // 64-K half within the 128-K chunk

        __syncthreads();   // t==0: also guards Phase-A LDS writes
        *(bf16x8*)&Bs[r1 * 72 + sac]      = w11;
        *(bf16x8*)&Bs[r1 * 72 + 32 + sac] = w12;
        *(bf16x8*)&Bs[r2 * 72 + sac]      = w21;
        *(bf16x8*)&Bs[r2 * 72 + 32 + sac] = w22;
        __syncthreads();

        // prefetch step t+1 (T14); at t==15, prefetch QKV slice 0 (if next)
        if (t < 15) {
            const int tn  = t + 1;
            const int nc  = tn >> 2, np = (tn >> 1) & 1, nh = tn & 1;
            if (np == 0) {
                const ushort* p = W1t + (size_t)(nc * 128) * 128 + nh * 64;
                w11 = *(const bf16x8*)(p + (size_t)r1 * 128 + sac);
                w12 = *(const bf16x8*)(p + (size_t)r1 * 128 + 32 + sac);
                w21 = *(const bf16x8*)(p + (size_t)r2 * 128 + sac);
                w22 = *(const bf16x8*)(p + (size_t)r2 * 128 + 32 + sac);
            } else {
                const ushort* p = W2t + nc * 128 + nh * 64;
                w11 = *(const bf16x8*)(p + (size_t)r1 * 512 + sac);
                w12 = *(const bf16x8*)(p + (size_t)r1 * 512 + 32 + sac);
                w21 = *(const bf16x8*)(p + (size_t)r2 * 512 + sac);
                w22 = *(const bf16x8*)(p + (size_t)r2 * 512 + 32 + sac);
            }
        } else if (do_next) {
            w11 = *(const bf16x8*)(wqn + (size_t)r1 * 128 + sac);
            w12 = *(const bf16x8*)(wqn + (size_t)r1 * 128 + 32 + sac);
            w21 = *(const bf16x8*)(wqn + (size_t)r2 * 128 + sac);
            w22 = *(const bf16x8*)(wqn + (size_t)r2 * 128 + 32 + sac);
        }

        const ushort* Asrc = ph ? Hcc : Af;
        #pragma unroll
        for (int hh = 0; hh < 2; ++hh) {
            const int kk = half * 64 + hh * 32;
            const bf16x8 af = *(const bf16x8*)&Asrc[(16 * wm + m16) * 136 + kk + quad * 8];
            bf16x8 bf[4];
            #pragma unroll
            for (int j = 0; j < 4; ++j)
                bf[j] = *(const bf16x8*)&Bs[(64 * wn + 16 * j + m16) * 72 + hh * 32 + quad * 8];
            if (ph == 0) {
                #pragma unroll
                for (int j = 0; j < 4; ++j)
                    acc[j] = __builtin_amdgcn_mfma_f32_16x16x32_bf16(af, bf[j], acc[j], 0, 0, 0);
            } else {
                #pragma unroll
                for (int j = 0; j < 4; ++j)
                    acc2[j] = __builtin_amdgcn_mfma_f32_16x16x32_bf16(af, bf[j], acc2[j], 0, 0, 0);
            }
        }

        if (ph == 0 && half == 1) {
            // FFN1 chunk cc complete: bias+ReLU -> Hcc (read by FFN2 steps,
            // ordered by the next step's first barrier)
            #pragma unroll
            for (int j = 0; j < 4; ++j) {
                const int col_l = 64 * wn + 16 * j + m16;
                const float bb = bias1[cc * 128 + col_l];
                #pragma unroll
                for (int r = 0; r < 4; ++r) {
                    const int row = 16 * wm + quad * 4 + r;
                    Hcc[row * 136 + col_l] = f32_to_bf16(fmaxf(acc[j][r] + bb, 0.f));
                }
                acc[j] = (f32x4)0.f;
            }
        }
    }

    // ---- Phase D: +bias2 +LN1-residual (vals), LN2 ----
    __syncthreads();

    float vreg[4][4];
    #pragma unroll
    for (int j = 0; j < 4; ++j) {
        const int col = 64 * wn + 16 * j + m16;
        const float bb = bias2[col];
        #pragma unroll
        for (int r = 0; r < 4; ++r) {
            const int row = 16 * wm + quad * 4 + r;
            float v = acc2[j][r] + bb + (float)vals[row * 132 + col];
            vreg[j][r] = v;
            vals[row * 132 + col] = (_Float16)v;
        }
    }
    if (last) {
        #pragma unroll
        for (int i = 0; i < 3; ++i) wo_s[tid + i * 256] = Wout[tid + i * 256];
    }
    __syncthreads();

    // parallel LN2 stats: 8 threads per row, 16 cols each, shfl-reduce
    {
        const int row = tid >> 3;
        const int c0  = (tid & 7) * 16;
        float s = 0.f, s2 = 0.f;
        #pragma unroll
        for (int u = 0; u < 4; ++u) {
            const f16x4 xv = *(const f16x4*)&vals[row * 132 + c0 + u * 4];
            #pragma unroll
            for (int e = 0; e < 4; ++e) {
                const float x = (float)xv[e];
                s += x; s2 = fmaf(x, x, s2);
            }
        }
        s  += __shfl_xor(s, 1, 64);  s  += __shfl_xor(s, 2, 64);  s  += __shfl_xor(s, 4, 64);
        s2 += __shfl_xor(s2, 1, 64); s2 += __shfl_xor(s2, 2, 64); s2 += __shfl_xor(s2, 4, 64);
        if ((tid & 7) == 0) {
            const float mu  = s * (1.f / 128.f);
            const float var = s2 * (1.f / 128.f) - mu * mu;
            mus[row]  = mu;
            rsds[row] = rsqrtf(var + 1e-6f);
        }
    }
    __syncthreads();

    if (!last) {
        // LN2 output: xb bf16 (next-layer residual) + Af bf16 (A-operand for
        // the fused next-layer QKV below). Same rounded value for both.
        #pragma unroll
        for (int j = 0; j < 4; ++j) {
            const int col = 64 * wn + 16 * j + m16;
            #pragma unroll
            for (int r = 0; r < 4; ++r) {
                const int row = 16 * wm + quad * 4 + r;
                const float rn = g2[col] * (vreg[j][r] - mus[row]) * rsds[row] + beta2[col];
                const ushort rb = f32_to_bf16(rn);
                xb[(size_t)(row0 + row) * Dq + col] = rb;
                Af[row * 136 + col] = rb;
            }
        }

        if (do_next) {
            // ---- next-layer QKV from resident Af; slice 0 already in regs
            //      (prefetched during pipeline step 15, in flight over Phase D)
            f32x4 qacc[4];
            #pragma unroll
            for (int st = 0; st < 6; ++st) {
                const int sel  = st >> 1;
                const int half = st & 1;
                if (half == 0) {
                    #pragma unroll
                    for (int j = 0; j < 4; ++j) qacc[j] = (f32x4)0.f;
                }

                __syncthreads();   // st==0: guards Af writes above
                *(bf16x8*)&Bs[r1 * 72 + sac]      = w11;
                *(bf16x8*)&Bs[r1 * 72 + 32 + sac] = w12;
                *(bf16x8*)&Bs[r2 * 72 + sac]      = w21;
                *(bf16x8*)&Bs[r2 * 72 + 32 + sac] = w22;
                __syncthreads();

                if (st < 5) {
                    const int sel2 = (st + 1) >> 1;
                    const int k02  = ((st + 1) & 1) * 64;
                    const ushort* Bt2 = (sel2 == 0) ? wqn : (sel2 == 1) ? wkn : wvn;
                    w11 = *(const bf16x8*)(Bt2 + (size_t)r1 * 128 + k02 + sac);
                    w12 = *(const bf16x8*)(Bt2 + (size_t)r1 * 128 + k02 + 32 + sac);
                    w21 = *(const bf16x8*)(Bt2 + (size_t)r2 * 128 + k02 + sac);
                    w22 = *(const bf16x8*)(Bt2 + (size_t)r2 * 128 + k02 + 32 + sac);
                }

                const int k0 = half * 64;
                #pragma unroll
                for (int hh = 0; hh < 2; ++hh) {
                    const int kk = k0 + hh * 32;
                    const bf16x8 af = *(const bf16x8*)&Af[(16 * wm + m16) * 136 + kk + quad * 8];
                    bf16x8 bf[4];
                    #pragma unroll
                    for (int j = 0; j < 4; ++j)
                        bf[j] = *(const bf16x8*)&Bs[(64 * wn + 16 * j + m16) * 72 + hh * 32 + quad * 8];
                    #pragma unroll
                    for (int j = 0; j < 4; ++j)
                        qacc[j] = __builtin_amdgcn_mfma_f32_16x16x32_bf16(af, bf[j], qacc[j], 0, 0, 0);
                }

                if (half) {
                    const float* bias = (sel == 0) ? bqn : (sel == 1) ? bkn : bvn;
                    const float  bscl = (sel == 0) ? QSCL : 1.0f;
                    #pragma unroll
                    for (int j = 0; j < 4; ++j) {
                        const int col = 64 * wn + 16 * j + m16;
                        const float bb = bias[col] * bscl;
                        const int hh = col >> 4, dh = col & 15;
                        #pragma unroll
                        for (int r = 0; r < 4; ++r) {
                            float val = fmaxf(qacc[j][r] + bb, 0.f);
                            const int gr = row0 + 16 * wm + quad * 4 + r;
                            const int b = gr >> 10, s = gr & 1023;
                            if (sel == 2) {
                                vo[(((size_t)b * Hq + hh) * DHq + dh) * Sq + s] = (_Float16)val;
                            } else {
                                _Float16* outp = (sel == 0) ? qo : ko;
                                outp[(((size_t)b * Hq + hh) * Sq + s) * DHq + dh] = (_Float16)val;
                            }
                        }
                    }
                }
            }
        }
    } else {
        #pragma unroll
        for (int j = 0; j < 4; ++j) {
            const int col = 64 * wn + 16 * j + m16;
            #pragma unroll
            for (int r = 0; r < 4; ++r) {
                const int row = 16 * wm + quad * 4 + r;
                vals[row * 132 + col] =
                    (_Float16)(g2[col] * (vreg[j][r] - mus[row]) * rsds[row] + beta2[col]);
            }
        }
        __syncthreads();
        if (tid < 32 * NCLS) {
            const int row = tid / NCLS;
            const int c   = tid - row * NCLS;
            float a = bout[c];
            #pragma unroll 8
            for (int kk = 0; kk < Dq; ++kk)
                a = fmaf((float)vals[row * 132 + kk], wo_s[kk * NCLS + c], a);
            out[(size_t)(row0 + row) * NCLS + c] = a;
        }
    }
}

// ---------------------------------------------------------------------------
// f16 MFMA flash attention — R6-proven champion: 2 Q-frags/wave, qc grid 8,
// single-buffered staging, T14 prefetch, denominator-MFMA, setprio.
// ---------------------------------------------------------------------------
__global__ __launch_bounds__(256) void attn_mfma(
    const _Float16* __restrict__ q, const _Float16* __restrict__ k,
    const _Float16* __restrict__ vt, _Float16* __restrict__ o)
{
    __shared__ _Float16 Ks[256 * 20];
    __shared__ _Float16 Vs[16 * 264];

    const int bh   = blockIdx.x;
    const int qc   = blockIdx.y;
    const int b    = bh >> 3;
    const int h    = bh & 7;
    const int tid  = threadIdx.x;
    const int wave = tid >> 6;
    const int lane = tid & 63;
    const int quad = lane >> 4;
    const int m16  = lane & 15;
    const int q0   = qc * 128 + wave * 32;

    const f16x4 qf0 = *(const f16x4*)(q + (((size_t)bh * Sq) + q0 + m16) * DHq + quad * 4);
    const f16x4 qf1 = *(const f16x4*)(q + (((size_t)bh * Sq) + q0 + 16 + m16) * DHq + quad * 4);

    const _Float16* kg  = k  + (size_t)bh * Sq * DHq;
    const _Float16* vtg = vt + (size_t)bh * DHq * Sq;

    f32x4 oacc0 = (f32x4)0.f, oacc1 = (f32x4)0.f;
    f32x4 dacc0 = (f32x4)0.f, dacc1 = (f32x4)0.f;

    f16x4 onesf;
    onesf[0] = (_Float16)1.f; onesf[1] = (_Float16)1.f;
    onesf[2] = (_Float16)1.f; onesf[3] = (_Float16)1.f;

    const int krow = tid;
    const int vrow = tid >> 4;
    const int vcol = (tid & 15) * 16;

    // prologue loads (kb = 0)
    f16x8 ka  = *(const f16x8*)(kg + (size_t)krow * DHq);
    f16x8 kb8 = *(const f16x8*)(kg + (size_t)krow * DHq + 8);
    f16x8 va  = *(const f16x8*)(vtg + (size_t)vrow * Sq + vcol);
    f16x8 vb  = *(const f16x8*)(vtg + (size_t)vrow * Sq + vcol + 8);

    for (int kb = 0; kb < 4; ++kb) {
        __syncthreads();
        *(f16x8*)&Ks[krow * 20 + 0] = ka;
        *(f16x8*)&Ks[krow * 20 + 8] = kb8;
        *(f16x8*)&Vs[vrow * 264 + vcol + 0] = va;
        *(f16x8*)&Vs[vrow * 264 + vcol + 8] = vb;
        __syncthreads();

        if (kb < 3) {      // issue next K/V tile loads BEFORE compute (T14)
            const _Float16* kp = kg  + ((size_t)(kb + 1) * 256 + krow) * DHq;
            const _Float16* vp = vtg + (size_t)vrow * Sq + (kb + 1) * 256 + vcol;
            ka  = *(const f16x8*)(kp);
            kb8 = *(const f16x8*)(kp + 8);
            va  = *(const f16x8*)(vp);
            vb  = *(const f16x8*)(vp + 8);
        }

        __builtin_amdgcn_s_setprio(1);
        #pragma unroll 4
        for (int kt = 0; kt < 16; ++kt) {
            const f16x4 kf = *(const f16x4*)&Ks[(kt * 16 + m16) * 20 + quad * 4];
            const f16x4 vf = *(const f16x4*)&Vs[m16 * 264 + kt * 16 + quad * 4];

            f32x4 st0 = __builtin_amdgcn_mfma_f32_16x16x16f16(kf, qf0, (f32x4)0.f, 0, 0, 0);
            f32x4 st1 = __builtin_amdgcn_mfma_f32_16x16x16f16(kf, qf1, (f32x4)0.f, 0, 0, 0);

            const f16x2 a0 = pkrtz(exp2_raw(st0[0]), exp2_raw(st0[1]));
            const f16x2 a1 = pkrtz(exp2_raw(st0[2]), exp2_raw(st0[3]));
            const f16x2 b0 = pkrtz(exp2_raw(st1[0]), exp2_raw(st1[1]));
            const f16x2 b1 = pkrtz(exp2_raw(st1[2]), exp2_raw(st1[3]));

            const f16x4 pf0 = __builtin_shufflevector(a0, a1, 0, 1, 2, 3);
            const f16x4 pf1 = __builtin_shufflevector(b0, b1, 0, 1, 2, 3);

            oacc0 = __builtin_amdgcn_mfma_f32_16x16x16f16(pf0, vf, oacc0, 0, 0, 0);
            oacc1 = __builtin_amdgcn_mfma_f32_16x16x16f16(pf1, vf, oacc1, 0, 0, 0);
            dacc0 = __builtin_amdgcn_mfma_f32_16x16x16f16(pf0, onesf, dacc0, 0, 0, 0);
            dacc1 = __builtin_amdgcn_mfma_f32_16x16x16f16(pf1, onesf, dacc1, 0, 0, 0);
        }
        __builtin_amdgcn_s_setprio(0);
    }

    // dacc[r] = full denominator for q-row (quad*4+r), replicated over cols —
    // exactly aligned with oacc[r]'s row. No cross-lane reduction needed.
    #pragma unroll
    for (int r = 0; r < 4; ++r) {
        const float i0 = rcp_fast(dacc0[r]);
        const float i1 = rcp_fast(dacc1[r]);
        o[((size_t)b * Sq + q0 + quad * 4 + r) * Dq + h * DHq + m16]      = (_Float16)(oacc0[r] * i0);
        o[((size_t)b * Sq + q0 + 16 + quad * 4 + r) * Dq + h * DHq + m16] = (_Float16)(oacc1[r] * i1);
    }
}

// ---------------------------------------------------------------------------
extern "C" void kernel_launch(void* const* d_in, const int* in_sizes, int n_in,
                              void* d_out, int out_size, void* d_ws, size_t ws_size,
                              hipStream_t stream)
{
    const float* x_in  = (const float*)d_in[0];
    const float* Wq    = (const float*)d_in[1];
    const float* bq    = (const float*)d_in[2];
    const float* Wk    = (const float*)d_in[3];
    const float* bk    = (const float*)d_in[4];
    const float* Wv    = (const float*)d_in[5];
    const float* bv    = (const float*)d_in[6];
    const float* ln1_g = (const float*)d_in[7];
    const float* ln1_b = (const float*)d_in[8];
    const float* W1    = (const float*)d_in[9];
    const float* b1    = (const float*)d_in[10];
    const float* W2    = (const float*)d_in[11];
    const float* b2    = (const float*)d_in[12];
    const float* ln2_g = (const float*)d_in[13];
    const float* ln2_b = (const float*)d_in[14];
    const float* Wout  = (const float*)d_in[15];
    const float* bout  = (const float*)d_in[16];
    float* out = (float*)d_out;

    float* ws = (float*)d_ws;
    _Float16* qf16 = (_Float16*)ws;                         // [0, 0.5NX)
    _Float16* kf16 = (_Float16*)(ws + NX / 2);              // [0.5, 1NX)
    _Float16* vt16 = (_Float16*)(ws + NX);                  // [1, 1.5NX)
    ushort*   xb   = (ushort*)(ws + 9 * NX / 2);            // [4.5, 5NX) bf16
    ushort*   xbf0 = (ushort*)(ws + 11 * NX / 2);           // [5.5, 6NX)
    ushort*   wbf  = (ushort*)(ws + 7 * NX);                // [7, ~7.26NX)
    _Float16* obuf = (_Float16*)(ws + 8 * NX);              // [8, 8.25NX) f16

    prep_kernel<<<dim3(2081), dim3(256), 0, stream>>>(Wq, Wk, Wv, W1, W2, x_in, wbf, xbf0);

    const dim3 blk(256);

    // layer-0 QKV (from x cast)
    {
        const ushort* wqt = wbf + (size_t)0 * 16384;
        const ushort* wkt = wbf + (size_t)3 * 16384;
        const ushort* wvt = wbf + (size_t)6 * 16384;
        gemm_qkv<<<dim3(256, 3), blk, 0, stream>>>(
            xbf0, wqt, wkt, wvt, bq, bk, bv, qf16, kf16, vt16);
    }

    const ushort* rcur = xbf0;   // bf16 residual stream (layer 0: cast of x)
    for (int l = 0; l < Lq; ++l) {
        const ushort* w1t = wbf + 147456 + (size_t)l * 65536;
        const ushort* w2t = wbf + 344064 + (size_t)l * 65536;
        const int next = (l < Lq - 1) ? 1 : 0;
        const int ln   = l + 1;
        const ushort* wqn = next ? (wbf + (size_t)(0 * 3 + ln) * 16384) : wbf;
        const ushort* wkn = next ? (wbf + (size_t)(1 * 3 + ln) * 16384) : wbf;
        const ushort* wvn = next ? (wbf + (size_t)(2 * 3 + ln) * 16384) : wbf;
        const float*  bqn = next ? (bq + ln * Dq) : bq;
        const float*  bkn = next ? (bk + ln * Dq) : bk;
        const float*  bvn = next ? (bv + ln * Dq) : bv;

        attn_mfma<<<dim3(Bq * Hq, 8), blk, 0, stream>>>(qf16, kf16, vt16, obuf);

        gemm_ffn_fused<<<dim3(512), blk, 0, stream>>>(
            obuf, rcur, ln1_g + l * Dq, ln1_b + l * Dq,
            w1t, b1 + l * DFFq, w2t, b2 + l * Dq,
            ln2_g + l * Dq, ln2_b + l * Dq,
            xb,
            wqn, wkn, wvn, bqn, bkn, bvn,
            qf16, kf16, vt16, next,
            Wout, bout, out, (l == Lq - 1) ? 1 : 0);

        rcur = xb;
    }
}

// Round 15
// 238.811 us; speedup vs baseline: 1.0195x; 1.0195x over previous
//
#include <hip/hip_runtime.h>
#include <math.h>

#define Bq 16
#define Sq 1024
#define Dq 128
#define Hq 8
#define DHq 16
#define DFFq 512
#define Lq 3
#define NCLS 6
#define NROWS (Bq * Sq)       // 16384
#define NX ((size_t)NROWS * Dq)   // 2,097,152 floats

// Q pre-scale: (1/sqrt(DH)) * log2(e), so softmax probs = 2^score (raw v_exp)
#define QSCL 0.36067376022224085f

typedef __attribute__((ext_vector_type(8))) short    bf16x8;
typedef __attribute__((ext_vector_type(4))) float    f32x4;
typedef __attribute__((ext_vector_type(4))) _Float16 f16x4;
typedef __attribute__((ext_vector_type(8))) _Float16 f16x8;
typedef __attribute__((ext_vector_type(2))) _Float16 f16x2;
typedef __attribute__((ext_vector_type(4))) ushort   u16x4;

__device__ inline ushort f32_to_bf16(float f) {
    union { float f; unsigned u; } v; v.f = f;
    unsigned r = v.u + 0x7fffu + ((v.u >> 16) & 1u);
    return (ushort)(r >> 16);
}

// raw 2^x via v_exp_f32 (ISA-guaranteed); avoids __expf's extra v_mul
__device__ __forceinline__ float exp2_raw(float x) {
    float r;
    asm("v_exp_f32 %0, %1" : "=v"(r) : "v"(x));
    return r;
}

__device__ __forceinline__ float rcp_fast(float x) {
    float r;
    asm("v_rcp_f32 %0, %1" : "=v"(r) : "v"(x));
    return r;
}

// pack two f32 -> f16x2 via v_cvt_pkrtz_f16_f32; builtin returns __fp16
// ext-vector, bit_cast to our _Float16 vector (same 4-byte layout).
__device__ __forceinline__ f16x2 pkrtz(float a, float b) {
    return __builtin_bit_cast(f16x2, __builtin_amdgcn_cvt_pkrtz(a, b));
}

// ---------------------------------------------------------------------------
// prep: LDS-tiled weight transposes (coalesced reads AND writes) + x cast.
// Wq PRE-SCALED by QSCL (ReLU commutes with positive scale).
// Grid 2081: blk 0..8 QKV, 9..20 W1 col-slices, 21..32 W2 row-slices,
// 33..2080 x-cast (vec4).
// ---------------------------------------------------------------------------
__global__ __launch_bounds__(256) void prep_kernel(
    const float* __restrict__ Wqp, const float* __restrict__ Wkp,
    const float* __restrict__ Wvp, const float* __restrict__ W1p,
    const float* __restrict__ W2p, const float* __restrict__ xp,
    ushort* __restrict__ wbf, ushort* __restrict__ xbf)
{
    __shared__ ushort tile[128 * 132];   // 33 KB; stride 132 (4-way, benign)
    const int blk = blockIdx.x;
    const int tid = threadIdx.x;

    if (blk < 33) {
        const float* S;
        int sld, dld;
        ushort* D;
        float scl = 1.0f;

        if (blk < 9) {                       // QKV: [128][128] -> [128][128]
            const int w = blk / 3, l = blk - w * 3;
            const float* src = (w == 0) ? Wqp : (w == 1) ? Wkp : Wvp;
            scl = (w == 0) ? QSCL : 1.0f;
            S   = src + (size_t)l * 16384;
            sld = 128;
            D   = wbf + (size_t)(w * 3 + l) * 16384;
            dld = 128;
        } else if (blk < 21) {               // W1: [128][512] col-slice t
            const int idx = blk - 9, l = idx >> 2, t = idx & 3;
            S   = W1p + (size_t)l * 65536 + t * 128;
            sld = 512;
            D   = wbf + 147456 + (size_t)l * 65536 + (size_t)t * 128 * 128;
            dld = 128;
        } else {                             // W2: [512][128] row-slice t
            const int idx = blk - 21, l = idx >> 2, t = idx & 3;
            S   = W2p + (size_t)l * 65536 + (size_t)t * 128 * 128;
            sld = 128;
            D   = wbf + 344064 + (size_t)l * 65536 + t * 128;
            dld = 512;
        }

        // phase 1: coalesced float4 reads of S rows -> tile[n][k] (bf16)
        #pragma unroll 4
        for (int i = 0; i < 16; ++i) {
            const int e4 = tid + i * 256;
            const int k  = e4 >> 5;
            const int n4 = (e4 & 31) * 4;
            const float4 v = *(const float4*)(S + (size_t)k * sld + n4);
            tile[(n4 + 0) * 132 + k] = f32_to_bf16(v.x * scl);
            tile[(n4 + 1) * 132 + k] = f32_to_bf16(v.y * scl);
            tile[(n4 + 2) * 132 + k] = f32_to_bf16(v.z * scl);
            tile[(n4 + 3) * 132 + k] = f32_to_bf16(v.w * scl);
        }
        __syncthreads();

        // phase 2: coalesced 8B stores of D rows (transposed data)
        const int k0 = (tid & 15) * 8;
        #pragma unroll
        for (int i = 0; i < 8; ++i) {
            const int n = (tid >> 4) + i * 16;
            const u16x4 a = *(const u16x4*)&tile[n * 132 + k0];
            const u16x4 b = *(const u16x4*)&tile[n * 132 + k0 + 4];
            *(u16x4*)(D + (size_t)n * dld + k0)     = a;
            *(u16x4*)(D + (size_t)n * dld + k0 + 4) = b;
        }
    } else {                                 // x cast, 4 elems/thread
        const size_t g = ((size_t)(blk - 33) * 256 + tid) * 4;
        const float4 xv = *(const float4*)(xp + g);
        u16x4 r;
        r[0] = f32_to_bf16(xv.x); r[1] = f32_to_bf16(xv.y);
        r[2] = f32_to_bf16(xv.z); r[3] = f32_to_bf16(xv.w);
        *(u16x4*)(xbf + g) = r;
    }
}

// ---------------------------------------------------------------------------
// Standalone QKV GEMM (layer 0 only). grid (256, 3).  [R3-proven]
// ---------------------------------------------------------------------------
__global__ __launch_bounds__(256) void gemm_qkv(
    const ushort* __restrict__ A,
    const ushort* __restrict__ wq, const ushort* __restrict__ wk,
    const ushort* __restrict__ wv,
    const float* __restrict__ bqp, const float* __restrict__ bkp,
    const float* __restrict__ bvp,
    _Float16* __restrict__ qo, _Float16* __restrict__ ko,
    _Float16* __restrict__ vo)
{
    __shared__ ushort As[64 * 40];
    __shared__ ushort Bs[128 * 40];

    const int sel  = blockIdx.y;
    const ushort* Bt   = (sel == 0) ? wq : (sel == 1) ? wk : wv;
    const float*  bias = (sel == 0) ? bqp : (sel == 1) ? bkp : bvp;
    const float   bscl = (sel == 0) ? QSCL : 1.0f;

    const int tid  = threadIdx.x;
    const int row0 = blockIdx.x * 64;
    const int wave = tid >> 6;
    const int lane = tid & 63;
    const int quad = lane >> 4;
    const int m16  = lane & 15;
    const int wm   = wave >> 1;
    const int wn   = wave & 1;

    const int sar = tid >> 2;
    const int sac = (tid & 3) * 8;

    f32x4 acc[2][4];
    #pragma unroll
    for (int i = 0; i < 2; ++i)
        #pragma unroll
        for (int j = 0; j < 4; ++j) acc[i][j] = (f32x4)0.f;

    const int r1 = tid >> 2, r2 = r1 + 64;

    // prologue: k0 = 0
    bf16x8 av  = *(const bf16x8*)(A  + (size_t)(row0 + sar) * 128 + sac);
    bf16x8 bv1 = *(const bf16x8*)(Bt + (size_t)r1 * 128 + sac);
    bf16x8 bv2 = *(const bf16x8*)(Bt + (size_t)r2 * 128 + sac);

    for (int k0 = 0; k0 < 128; k0 += 32) {
        __syncthreads();
        *(bf16x8*)&As[sar * 40 + sac] = av;
        *(bf16x8*)&Bs[r1 * 40 + sac]  = bv1;
        *(bf16x8*)&Bs[r2 * 40 + sac]  = bv2;
        __syncthreads();

        if (k0 < 96) {
            av  = *(const bf16x8*)(A  + (size_t)(row0 + sar) * 128 + k0 + 32 + sac);
            bv1 = *(const bf16x8*)(Bt + (size_t)r1 * 128 + k0 + 32 + sac);
            bv2 = *(const bf16x8*)(Bt + (size_t)r2 * 128 + k0 + 32 + sac);
        }

        bf16x8 af[2], bf[4];
        #pragma unroll
        for (int i = 0; i < 2; ++i)
            af[i] = *(const bf16x8*)&As[(32 * wm + 16 * i + m16) * 40 + quad * 8];
        #pragma unroll
        for (int j = 0; j < 4; ++j)
            bf[j] = *(const bf16x8*)&Bs[(64 * wn + 16 * j + m16) * 40 + quad * 8];
        #pragma unroll
        for (int i = 0; i < 2; ++i)
            #pragma unroll
            for (int j = 0; j < 4; ++j)
                acc[i][j] = __builtin_amdgcn_mfma_f32_16x16x32_bf16(af[i], bf[j], acc[i][j], 0, 0, 0);
    }

    #pragma unroll
    for (int i = 0; i < 2; ++i) {
        #pragma unroll
        for (int j = 0; j < 4; ++j) {
            const int col = 64 * wn + 16 * j + m16;
            const float bb = bias[col] * bscl;
            const int hh = col >> 4, dh = col & 15;
            #pragma unroll
            for (int r = 0; r < 4; ++r) {
                float val = fmaxf(acc[i][j][r] + bb, 0.f);
                const int gr = row0 + 32 * wm + 16 * i + quad * 4 + r;
                const int b = gr >> 10, s = gr & 1023;
                if (sel == 2) {
                    vo[(((size_t)b * Hq + hh) * DHq + dh) * Sq + s] = (_Float16)val;
                } else {
                    _Float16* outp = (sel == 0) ? qo : ko;
                    outp[(((size_t)b * Hq + hh) * Sq + s) * DHq + dh] = (_Float16)val;
                }
            }
        }
    }
}

// ---------------------------------------------------------------------------
// FUSED FFN BLOCK: LN1 -> (FFN1-chunk -> FFN2-partial)x4 -> LN2 + QKV.
// [R6-proven champion: chunk-interleaved, 44.5 KB LDS, 32-row blocks, grid 512]
// ---------------------------------------------------------------------------
__global__ __launch_bounds__(256, 3) void gemm_ffn_fused(
    const _Float16* __restrict__ o, const float* __restrict__ resid,
    const float* __restrict__ g1, const float* __restrict__ beta1,
    const ushort* __restrict__ W1t, const float* __restrict__ bias1,
    const ushort* __restrict__ W2t, const float* __restrict__ bias2,
    const float* __restrict__ g2, const float* __restrict__ beta2,
    float* __restrict__ xb,
    const ushort* __restrict__ wqn, const ushort* __restrict__ wkn,
    const ushort* __restrict__ wvn,
    const float* __restrict__ bqn, const float* __restrict__ bkn,
    const float* __restrict__ bvn,
    _Float16* __restrict__ qo, _Float16* __restrict__ ko,
    _Float16* __restrict__ vo, int do_next,
    const float* __restrict__ Wout, const float* __restrict__ bout,
    float* __restrict__ out, int last)
{
    __shared__ __align__(16) char smem[44544];
    ushort*    Af   = (ushort*)smem;                 // 32x136 bf16 (LN1 out)
    ushort*    Hcc  = (ushort*)(smem + 8704);        // 32x136 bf16 (h chunk)
    ushort*    Bs   = (ushort*)(smem + 17408);       // 128x72 staging
    float*     wo_s = (float*)(smem + 17408);        // overlays Bs (last, post-GEMM)
    _Float16*  vals = (_Float16*)(smem + 35840);     // 32x132 f16
    float*     mus  = (float*)(smem + 44288);
    float*     rsds = (float*)(smem + 44416);

    const int tid  = threadIdx.x;
    const int row0 = blockIdx.x * 32;
    const int wave = tid >> 6;
    const int lane = tid & 63;
    const int quad = lane >> 4;
    const int m16  = lane & 15;
    const int wm   = wave >> 1;          // row half: 16*wm
    const int wn   = wave & 1;           // col half: 64*wn
    const int sac  = (tid & 3) * 8;
    const int r1   = tid >> 2, r2 = r1 + 64;

    // ---- Phase A: LN1, 8 rows/wave; batch-issue all 16 global loads ----
    const int ca = lane * 2;
    const float2 gg  = *(const float2*)(g1 + ca);
    const float2 bt1 = *(const float2*)(beta1 + ca);
    f16x2  ovv[8];
    float2 rvv[8];
    #pragma unroll
    for (int it = 0; it < 8; ++it) {
        const size_t base = (size_t)(row0 + wave * 8 + it) * Dq;
        ovv[it] = *(const f16x2*)(o + base + ca);
        rvv[it] = *(const float2*)(resid + base + ca);
    }
    #pragma unroll
    for (int it = 0; it < 8; ++it) {
        const int rr = wave * 8 + it;
        const float v0 = (float)ovv[it][0] + rvv[it].x;
        const float v1 = (float)ovv[it][1] + rvv[it].y;

        float s = v0 + v1;
        #pragma unroll
        for (int off = 32; off > 0; off >>= 1) s += __shfl_xor(s, off, 64);
        const float mu = s * (1.f / 128.f);
        const float d0 = v0 - mu, d1 = v1 - mu;
        float vs = d0 * d0 + d1 * d1;
        #pragma unroll
        for (int off = 32; off > 0; off >>= 1) vs += __shfl_xor(vs, off, 64);
        const float rstd = rsqrtf(vs * (1.f / 128.f) + 1e-8f);

        const float rv0 = gg.x * d0 * rstd + bt1.x;
        const float rv1 = gg.y * d1 * rstd + bt1.y;
        ushort2 ab; ab.x = f32_to_bf16(rv0); ab.y = f32_to_bf16(rv1);
        *(ushort2*)&Af[rr * 136 + ca] = ab;
        f16x2 vv; vv[0] = (_Float16)rv0; vv[1] = (_Float16)rv1;
        *(f16x2*)&vals[rr * 132 + ca] = vv;
    }

    // ---- Unified 16-step pipeline: per chunk cc: FFN1 (2 steps) then
    //      FFN2 partial-K (2 steps). acc2 accumulates across all chunks. ----
    f32x4 acc[4], acc2[4];
    #pragma unroll
    for (int j = 0; j < 4; ++j) { acc[j] = (f32x4)0.f; acc2[j] = (f32x4)0.f; }

    // prologue: step 0 = W1 chunk 0, half 0
    bf16x8 w11 = *(const bf16x8*)(W1t + (size_t)r1 * 128 + sac);
    bf16x8 w12 = *(const bf16x8*)(W1t + (size_t)r1 * 128 + 32 + sac);
    bf16x8 w21 = *(const bf16x8*)(W1t + (size_t)r2 * 128 + sac);
    bf16x8 w22 = *(const bf16x8*)(W1t + (size_t)r2 * 128 + 32 + sac);

    #pragma unroll
    for (int t = 0; t < 16; ++t) {
        const int cc   = t >> 2;
        const int ph   = (t >> 1) & 1;     // 0 = FFN1 (W1), 1 = FFN2 (W2)
        const int half = t & 1;            // 64-K half within the 128-K chunk

        __syncthreads();   // t==0: also guards Phase-A LDS writes
        *(bf16x8*)&Bs[r1 * 72 + sac]      = w11;
        *(bf16x8*)&Bs[r1 * 72 + 32 + sac] = w12;
        *(bf16x8*)&Bs[r2 * 72 + sac]      = w21;
        *(bf16x8*)&Bs[r2 * 72 + 32 + sac] = w22;
        __syncthreads();

        // prefetch step t+1 (T14); at t==15, prefetch QKV slice 0 (if next)
        if (t < 15) {
            const int tn  = t + 1;
            const int nc  = tn >> 2, np = (tn >> 1) & 1, nh = tn & 1;
            if (np == 0) {
                const ushort* p = W1t + (size_t)(nc * 128) * 128 + nh * 64;
                w11 = *(const bf16x8*)(p + (size_t)r1 * 128 + sac);
                w12 = *(const bf16x8*)(p + (size_t)r1 * 128 + 32 + sac);
                w21 = *(const bf16x8*)(p + (size_t)r2 * 128 + sac);
                w22 = *(const bf16x8*)(p + (size_t)r2 * 128 + 32 + sac);
            } else {
                const ushort* p = W2t + nc * 128 + nh * 64;
                w11 = *(const bf16x8*)(p + (size_t)r1 * 512 + sac);
                w12 = *(const bf16x8*)(p + (size_t)r1 * 512 + 32 + sac);
                w21 = *(const bf16x8*)(p + (size_t)r2 * 512 + sac);
                w22 = *(const bf16x8*)(p + (size_t)r2 * 512 + 32 + sac);
            }
        } else if (do_next) {
            w11 = *(const bf16x8*)(wqn + (size_t)r1 * 128 + sac);
            w12 = *(const bf16x8*)(wqn + (size_t)r1 * 128 + 32 + sac);
            w21 = *(const bf16x8*)(wqn + (size_t)r2 * 128 + sac);
            w22 = *(const bf16x8*)(wqn + (size_t)r2 * 128 + 32 + sac);
        }

        const ushort* Asrc = ph ? Hcc : Af;
        #pragma unroll
        for (int hh = 0; hh < 2; ++hh) {
            const int kk = half * 64 + hh * 32;
            const bf16x8 af = *(const bf16x8*)&Asrc[(16 * wm + m16) * 136 + kk + quad * 8];
            bf16x8 bf[4];
            #pragma unroll
            for (int j = 0; j < 4; ++j)
                bf[j] = *(const bf16x8*)&Bs[(64 * wn + 16 * j + m16) * 72 + hh * 32 + quad * 8];
            if (ph == 0) {
                #pragma unroll
                for (int j = 0; j < 4; ++j)
                    acc[j] = __builtin_amdgcn_mfma_f32_16x16x32_bf16(af, bf[j], acc[j], 0, 0, 0);
            } else {
                #pragma unroll
                for (int j = 0; j < 4; ++j)
                    acc2[j] = __builtin_amdgcn_mfma_f32_16x16x32_bf16(af, bf[j], acc2[j], 0, 0, 0);
            }
        }

        if (ph == 0 && half == 1) {
            // FFN1 chunk cc complete: bias+ReLU -> Hcc (read by FFN2 steps,
            // ordered by the next step's first barrier)
            #pragma unroll
            for (int j = 0; j < 4; ++j) {
                const int col_l = 64 * wn + 16 * j + m16;
                const float bb = bias1[cc * 128 + col_l];
                #pragma unroll
                for (int r = 0; r < 4; ++r) {
                    const int row = 16 * wm + quad * 4 + r;
                    Hcc[row * 136 + col_l] = f32_to_bf16(fmaxf(acc[j][r] + bb, 0.f));
                }
                acc[j] = (f32x4)0.f;
            }
        }
    }

    // ---- Phase D: +bias2 +LN1-residual (vals), LN2 ----
    __syncthreads();

    float vreg[4][4];
    #pragma unroll
    for (int j = 0; j < 4; ++j) {
        const int col = 64 * wn + 16 * j + m16;
        const float bb = bias2[col];
        #pragma unroll
        for (int r = 0; r < 4; ++r) {
            const int row = 16 * wm + quad * 4 + r;
            float v = acc2[j][r] + bb + (float)vals[row * 132 + col];
            vreg[j][r] = v;
            vals[row * 132 + col] = (_Float16)v;
        }
    }
    if (last) {
        #pragma unroll
        for (int i = 0; i < 3; ++i) wo_s[tid + i * 256] = Wout[tid + i * 256];
    }
    __syncthreads();

    // parallel LN2 stats: 8 threads per row, 16 cols each, shfl-reduce
    {
        const int row = tid >> 3;
        const int c0  = (tid & 7) * 16;
        float s = 0.f, s2 = 0.f;
        #pragma unroll
        for (int u = 0; u < 4; ++u) {
            const f16x4 xv = *(const f16x4*)&vals[row * 132 + c0 + u * 4];
            #pragma unroll
            for (int e = 0; e < 4; ++e) {
                const float x = (float)xv[e];
                s += x; s2 = fmaf(x, x, s2);
            }
        }
        s  += __shfl_xor(s, 1, 64);  s  += __shfl_xor(s, 2, 64);  s  += __shfl_xor(s, 4, 64);
        s2 += __shfl_xor(s2, 1, 64); s2 += __shfl_xor(s2, 2, 64); s2 += __shfl_xor(s2, 4, 64);
        if ((tid & 7) == 0) {
            const float mu  = s * (1.f / 128.f);
            const float var = s2 * (1.f / 128.f) - mu * mu;
            mus[row]  = mu;
            rsds[row] = rsqrtf(var + 1e-6f);
        }
    }
    __syncthreads();

    if (!last) {
        // LN2 output: xb f32 (next-layer residual) + Af bf16 (A-operand for
        // the fused next-layer QKV below).
        #pragma unroll
        for (int j = 0; j < 4; ++j) {
            const int col = 64 * wn + 16 * j + m16;
            #pragma unroll
            for (int r = 0; r < 4; ++r) {
                const int row = 16 * wm + quad * 4 + r;
                const float rn = g2[col] * (vreg[j][r] - mus[row]) * rsds[row] + beta2[col];
                xb[(size_t)(row0 + row) * Dq + col] = rn;
                Af[row * 136 + col] = f32_to_bf16(rn);
            }
        }

        if (do_next) {
            // ---- next-layer QKV from resident Af; slice 0 already in regs
            //      (prefetched during pipeline step 15, in flight over Phase D)
            f32x4 qacc[4];
            #pragma unroll
            for (int st = 0; st < 6; ++st) {
                const int sel  = st >> 1;
                const int half = st & 1;
                if (half == 0) {
                    #pragma unroll
                    for (int j = 0; j < 4; ++j) qacc[j] = (f32x4)0.f;
                }

                __syncthreads();   // st==0: guards Af writes above
                *(bf16x8*)&Bs[r1 * 72 + sac]      = w11;
                *(bf16x8*)&Bs[r1 * 72 + 32 + sac] = w12;
                *(bf16x8*)&Bs[r2 * 72 + sac]      = w21;
                *(bf16x8*)&Bs[r2 * 72 + 32 + sac] = w22;
                __syncthreads();

                if (st < 5) {
                    const int sel2 = (st + 1) >> 1;
                    const int k02  = ((st + 1) & 1) * 64;
                    const ushort* Bt2 = (sel2 == 0) ? wqn : (sel2 == 1) ? wkn : wvn;
                    w11 = *(const bf16x8*)(Bt2 + (size_t)r1 * 128 + k02 + sac);
                    w12 = *(const bf16x8*)(Bt2 + (size_t)r1 * 128 + k02 + 32 + sac);
                    w21 = *(const bf16x8*)(Bt2 + (size_t)r2 * 128 + k02 + sac);
                    w22 = *(const bf16x8*)(Bt2 + (size_t)r2 * 128 + k02 + 32 + sac);
                }

                const int k0 = half * 64;
                #pragma unroll
                for (int hh = 0; hh < 2; ++hh) {
                    const int kk = k0 + hh * 32;
                    const bf16x8 af = *(const bf16x8*)&Af[(16 * wm + m16) * 136 + kk + quad * 8];
                    bf16x8 bf[4];
                    #pragma unroll
                    for (int j = 0; j < 4; ++j)
                        bf[j] = *(const bf16x8*)&Bs[(64 * wn + 16 * j + m16) * 72 + hh * 32 + quad * 8];
                    #pragma unroll
                    for (int j = 0; j < 4; ++j)
                        qacc[j] = __builtin_amdgcn_mfma_f32_16x16x32_bf16(af, bf[j], qacc[j], 0, 0, 0);
                }

                if (half) {
                    const float* bias = (sel == 0) ? bqn : (sel == 1) ? bkn : bvn;
                    const float  bscl = (sel == 0) ? QSCL : 1.0f;
                    #pragma unroll
                    for (int j = 0; j < 4; ++j) {
                        const int col = 64 * wn + 16 * j + m16;
                        const float bb = bias[col] * bscl;
                        const int hh = col >> 4, dh = col & 15;
                        #pragma unroll
                        for (int r = 0; r < 4; ++r) {
                            float val = fmaxf(qacc[j][r] + bb, 0.f);
                            const int gr = row0 + 16 * wm + quad * 4 + r;
                            const int b = gr >> 10, s = gr & 1023;
                            if (sel == 2) {
                                vo[(((size_t)b * Hq + hh) * DHq + dh) * Sq + s] = (_Float16)val;
                            } else {
                                _Float16* outp = (sel == 0) ? qo : ko;
                                outp[(((size_t)b * Hq + hh) * Sq + s) * DHq + dh] = (_Float16)val;
                            }
                        }
                    }
                }
            }
        }
    } else {
        #pragma unroll
        for (int j = 0; j < 4; ++j) {
            const int col = 64 * wn + 16 * j + m16;
            #pragma unroll
            for (int r = 0; r < 4; ++r) {
                const int row = 16 * wm + quad * 4 + r;
                vals[row * 132 + col] =
                    (_Float16)(g2[col] * (vreg[j][r] - mus[row]) * rsds[row] + beta2[col]);
            }
        }
        __syncthreads();
        if (tid < 32 * NCLS) {
            const int row = tid / NCLS;
            const int c   = tid - row * NCLS;
            float a = bout[c];
            #pragma unroll 8
            for (int kk = 0; kk < Dq; ++kk)
                a = fmaf((float)vals[row * 132 + kk], wo_s[kk * NCLS + c], a);
            out[(size_t)(row0 + row) * NCLS + c] = a;
        }
    }
}

// ---------------------------------------------------------------------------
// f16 MFMA flash attention — R6-proven champion: 2 Q-frags/wave, qc grid 8,
// single-buffered staging, T14 prefetch, denominator-MFMA, setprio.
// ---------------------------------------------------------------------------
__global__ __launch_bounds__(256) void attn_mfma(
    const _Float16* __restrict__ q, const _Float16* __restrict__ k,
    const _Float16* __restrict__ vt, _Float16* __restrict__ o)
{
    __shared__ _Float16 Ks[256 * 20];
    __shared__ _Float16 Vs[16 * 264];

    const int bh   = blockIdx.x;
    const int qc   = blockIdx.y;
    const int b    = bh >> 3;
    const int h    = bh & 7;
    const int tid  = threadIdx.x;
    const int wave = tid >> 6;
    const int lane = tid & 63;
    const int quad = lane >> 4;
    const int m16  = lane & 15;
    const int q0   = qc * 128 + wave * 32;

    const f16x4 qf0 = *(const f16x4*)(q + (((size_t)bh * Sq) + q0 + m16) * DHq + quad * 4);
    const f16x4 qf1 = *(const f16x4*)(q + (((size_t)bh * Sq) + q0 + 16 + m16) * DHq + quad * 4);

    const _Float16* kg  = k  + (size_t)bh * Sq * DHq;
    const _Float16* vtg = vt + (size_t)bh * DHq * Sq;

    f32x4 oacc0 = (f32x4)0.f, oacc1 = (f32x4)0.f;
    f32x4 dacc0 = (f32x4)0.f, dacc1 = (f32x4)0.f;

    f16x4 onesf;
    onesf[0] = (_Float16)1.f; onesf[1] = (_Float16)1.f;
    onesf[2] = (_Float16)1.f; onesf[3] = (_Float16)1.f;

    const int krow = tid;
    const int vrow = tid >> 4;
    const int vcol = (tid & 15) * 16;

    // prologue loads (kb = 0)
    f16x8 ka  = *(const f16x8*)(kg + (size_t)krow * DHq);
    f16x8 kb8 = *(const f16x8*)(kg + (size_t)krow * DHq + 8);
    f16x8 va  = *(const f16x8*)(vtg + (size_t)vrow * Sq + vcol);
    f16x8 vb  = *(const f16x8*)(vtg + (size_t)vrow * Sq + vcol + 8);

    for (int kb = 0; kb < 4; ++kb) {
        __syncthreads();
        *(f16x8*)&Ks[krow * 20 + 0] = ka;
        *(f16x8*)&Ks[krow * 20 + 8] = kb8;
        *(f16x8*)&Vs[vrow * 264 + vcol + 0] = va;
        *(f16x8*)&Vs[vrow * 264 + vcol + 8] = vb;
        __syncthreads();

        if (kb < 3) {      // issue next K/V tile loads BEFORE compute (T14)
            const _Float16* kp = kg  + ((size_t)(kb + 1) * 256 + krow) * DHq;
            const _Float16* vp = vtg + (size_t)vrow * Sq + (kb + 1) * 256 + vcol;
            ka  = *(const f16x8*)(kp);
            kb8 = *(const f16x8*)(kp + 8);
            va  = *(const f16x8*)(vp);
            vb  = *(const f16x8*)(vp + 8);
        }

        __builtin_amdgcn_s_setprio(1);
        #pragma unroll 4
        for (int kt = 0; kt < 16; ++kt) {
            const f16x4 kf = *(const f16x4*)&Ks[(kt * 16 + m16) * 20 + quad * 4];
            const f16x4 vf = *(const f16x4*)&Vs[m16 * 264 + kt * 16 + quad * 4];

            f32x4 st0 = __builtin_amdgcn_mfma_f32_16x16x16f16(kf, qf0, (f32x4)0.f, 0, 0, 0);
            f32x4 st1 = __builtin_amdgcn_mfma_f32_16x16x16f16(kf, qf1, (f32x4)0.f, 0, 0, 0);

            const f16x2 a0 = pkrtz(exp2_raw(st0[0]), exp2_raw(st0[1]));
            const f16x2 a1 = pkrtz(exp2_raw(st0[2]), exp2_raw(st0[3]));
            const f16x2 b0 = pkrtz(exp2_raw(st1[0]), exp2_raw(st1[1]));
            const f16x2 b1 = pkrtz(exp2_raw(st1[2]), exp2_raw(st1[3]));

            const f16x4 pf0 = __builtin_shufflevector(a0, a1, 0, 1, 2, 3);
            const f16x4 pf1 = __builtin_shufflevector(b0, b1, 0, 1, 2, 3);

            oacc0 = __builtin_amdgcn_mfma_f32_16x16x16f16(pf0, vf, oacc0, 0, 0, 0);
            oacc1 = __builtin_amdgcn_mfma_f32_16x16x16f16(pf1, vf, oacc1, 0, 0, 0);
            dacc0 = __builtin_amdgcn_mfma_f32_16x16x16f16(pf0, onesf, dacc0, 0, 0, 0);
            dacc1 = __builtin_amdgcn_mfma_f32_16x16x16f16(pf1, onesf, dacc1, 0, 0, 0);
        }
        __builtin_amdgcn_s_setprio(0);
    }

    // dacc[r] = full denominator for q-row (quad*4+r), replicated over cols —
    // exactly aligned with oacc[r]'s row. No cross-lane reduction needed.
    #pragma unroll
    for (int r = 0; r < 4; ++r) {
        const float i0 = rcp_fast(dacc0[r]);
        const float i1 = rcp_fast(dacc1[r]);
        o[((size_t)b * Sq + q0 + quad * 4 + r) * Dq + h * DHq + m16]      = (_Float16)(oacc0[r] * i0);
        o[((size_t)b * Sq + q0 + 16 + quad * 4 + r) * Dq + h * DHq + m16] = (_Float16)(oacc1[r] * i1);
    }
}

// ---------------------------------------------------------------------------
extern "C" void kernel_launch(void* const* d_in, const int* in_sizes, int n_in,
                              void* d_out, int out_size, void* d_ws, size_t ws_size,
                              hipStream_t stream)
{
    const float* x_in  = (const float*)d_in[0];
    const float* Wq    = (const float*)d_in[1];
    const float* bq    = (const float*)d_in[2];
    const float* Wk    = (const float*)d_in[3];
    const float* bk    = (const float*)d_in[4];
    const float* Wv    = (const float*)d_in[5];
    const float* bv    = (const float*)d_in[6];
    const float* ln1_g = (const float*)d_in[7];
    const float* ln1_b = (const float*)d_in[8];
    const float* W1    = (const float*)d_in[9];
    const float* b1    = (const float*)d_in[10];
    const float* W2    = (const float*)d_in[11];
    const float* b2    = (const float*)d_in[12];
    const float* ln2_g = (const float*)d_in[13];
    const float* ln2_b = (const float*)d_in[14];
    const float* Wout  = (const float*)d_in[15];
    const float* bout  = (const float*)d_in[16];
    float* out = (float*)d_out;

    float* ws = (float*)d_ws;
    _Float16* qf16 = (_Float16*)ws;                         // [0, 0.5NX)
    _Float16* kf16 = (_Float16*)(ws + NX / 2);              // [0.5, 1NX)
    _Float16* vt16 = (_Float16*)(ws + NX);                  // [1, 1.5NX)
    float*    xb   = ws + 9 * NX / 2;                       // [4.5, 5.5NX)
    ushort*   xbf0 = (ushort*)(ws + 11 * NX / 2);           // [5.5, 6NX)
    ushort*   wbf  = (ushort*)(ws + 7 * NX);                // [7, ~7.26NX)
    _Float16* obuf = (_Float16*)(ws + 8 * NX);              // [8, 8.25NX) f16

    prep_kernel<<<dim3(2081), dim3(256), 0, stream>>>(Wq, Wk, Wv, W1, W2, x_in, wbf, xbf0);

    const dim3 blk(256);

    // layer-0 QKV (from x cast)
    {
        const ushort* wqt = wbf + (size_t)0 * 16384;
        const ushort* wkt = wbf + (size_t)3 * 16384;
        const ushort* wvt = wbf + (size_t)6 * 16384;
        gemm_qkv<<<dim3(256, 3), blk, 0, stream>>>(
            xbf0, wqt, wkt, wvt, bq, bk, bv, qf16, kf16, vt16);
    }

    const float* xcur = x_in;
    for (int l = 0; l < Lq; ++l) {
        const ushort* w1t = wbf + 147456 + (size_t)l * 65536;
        const ushort* w2t = wbf + 344064 + (size_t)l * 65536;
        const int next = (l < Lq - 1) ? 1 : 0;
        const int ln   = l + 1;
        const ushort* wqn = next ? (wbf + (size_t)(0 * 3 + ln) * 16384) : wbf;
        const ushort* wkn = next ? (wbf + (size_t)(1 * 3 + ln) * 16384) : wbf;
        const ushort* wvn = next ? (wbf + (size_t)(2 * 3 + ln) * 16384) : wbf;
        const float*  bqn = next ? (bq + ln * Dq) : bq;
        const float*  bkn = next ? (bk + ln * Dq) : bk;
        const float*  bvn = next ? (bv + ln * Dq) : bv;

        attn_mfma<<<dim3(Bq * Hq, 8), blk, 0, stream>>>(qf16, kf16, vt16, obuf);

        gemm_ffn_fused<<<dim3(512), blk, 0, stream>>>(
            obuf, xcur, ln1_g + l * Dq, ln1_b + l * Dq,
            w1t, b1 + l * DFFq, w2t, b2 + l * Dq,
            ln2_g + l * Dq, ln2_b + l * Dq,
            xb,
            wqn, wkn, wvn, bqn, bkn, bvn,
            qf16, kf16, vt16, next,
            Wout, bout, out, (l == Lq - 1) ? 1 : 0);

        xcur = xb;
    }
}